// Round 1
// baseline (181.116 us; speedup 1.0000x reference)
//
#include <hip/hip_runtime.h>

#define NUM 16

// One thread per (batch, track). All 4x4 algebra in registers, F-structure
// exploited (F P F^T = row-adds + col-adds). Memory-bound: ~189 MB traffic.
__global__ __launch_bounds__(256) void kf_update_kernel(
    const float* __restrict__ value,   // (B, 32)
    const float* __restrict__ vel,     // (B, 32)
    const float* __restrict__ Pin,     // (B, 16, 4, 4)
    const float* __restrict__ obs,     // (B, 32)
    const int*   __restrict__ lm,      // (B, 16)
    const int*   __restrict__ mask,    // (B, 16)
    float* __restrict__ out,           // rv(B*32) | rm(B*16) | rvel(B*32) | rP(B*256)
    int Bn)
{
    const int tid = blockIdx.x * blockDim.x + threadIdx.x;
    const int total = Bn * NUM;
    if (tid >= total) return;

    // ---- loads (vectorized, coalesced) ----
    const float2 v = reinterpret_cast<const float2*>(value)[tid];
    const float2 u = reinterpret_cast<const float2*>(vel)[tid];
    const float2 o = reinterpret_cast<const float2*>(obs)[tid];
    float Pm[16];
    {
        const float4* Pp = reinterpret_cast<const float4*>(Pin) + (size_t)tid * 4;
        float4 r0 = Pp[0], r1 = Pp[1], r2 = Pp[2], r3 = Pp[3];
        Pm[0]=r0.x; Pm[1]=r0.y; Pm[2]=r0.z; Pm[3]=r0.w;
        Pm[4]=r1.x; Pm[5]=r1.y; Pm[6]=r1.z; Pm[7]=r1.w;
        Pm[8]=r2.x; Pm[9]=r2.y; Pm[10]=r2.z; Pm[11]=r2.w;
        Pm[12]=r3.x; Pm[13]=r3.y; Pm[14]=r3.z; Pm[15]=r3.w;
    }
    const int l = lm[tid];
    const int m = mask[tid];

    // ---- predict: pred = F @ [vx,vy,ux,uy] ----
    const float p0 = v.x + u.x;
    const float p1 = v.y + u.y;
    const float p2 = u.x;
    const float p3 = u.y;

    // ---- pP = F P F^T: Q = F P (row adds), then pP = Q F^T (col adds) ----
    float Q[4][4];
    #pragma unroll
    for (int j = 0; j < 4; ++j) {
        Q[0][j] = Pm[0*4+j] + Pm[2*4+j];
        Q[1][j] = Pm[1*4+j] + Pm[3*4+j];
        Q[2][j] = Pm[2*4+j];
        Q[3][j] = Pm[3*4+j];
    }
    float pP[4][4];
    #pragma unroll
    for (int i = 0; i < 4; ++i) {
        pP[i][0] = Q[i][0] + Q[i][2];
        pP[i][1] = Q[i][1] + Q[i][3];
        pP[i][2] = Q[i][2];
        pP[i][3] = Q[i][3];
    }

    // ---- innovation covariance S = pP[:2,:2] + 1e-5 I, closed-form 2x2 inv ----
    const float S00 = pP[0][0] + 1e-5f;
    const float S01 = pP[0][1];
    const float S10 = pP[1][0];
    const float S11 = pP[1][1] + 1e-5f;
    const float det = S00 * S11 - S01 * S10;
    const float rdet = 1.0f / det;

    // ---- Kalman gain K = pP[:, :2] @ Sinv ----
    float K0[4], K1[4];
    #pragma unroll
    for (int i = 0; i < 4; ++i) {
        K0[i] = (pP[i][0] * S11 - pP[i][1] * S10) * rdet;
        K1[i] = (pP[i][1] * S00 - pP[i][0] * S01) * rdet;
    }

    // ---- state update ----
    const float y0 = o.x - p0;
    const float y1 = o.y - p1;
    const float upd0 = p0 + K0[0] * y0 + K1[0] * y1;
    const float upd1 = p1 + K0[1] * y0 + K1[1] * y1;
    const float upd2 = p2 + K0[2] * y0 + K1[2] * y1;
    const float upd3 = p3 + K0[3] * y0 + K1[3] * y1;

    // ---- covariance update Pn = pP - K @ pP[:2, :] ----
    float Pn[4][4];
    #pragma unroll
    for (int i = 0; i < 4; ++i) {
        #pragma unroll
        for (int j = 0; j < 4; ++j) {
            Pn[i][j] = pP[i][j] - (K0[i] * pP[0][j] + K1[i] * pP[1][j]);
        }
    }

    // ---- condition table ----
    const bool c1  = (l == 0) && (m == 0);
    const bool c2  = (l == 0) && (m != 0);
    const bool c3  = (l != 0) && (m == 0);
    const bool c4  = (l != 0) && (m != 0);
    const bool c3a = c3 && (l <= 5);

    const float rv0  = c4 ? upd0 : (c3 ? p0 : o.x);
    const float rv1  = c4 ? upd1 : (c3 ? p1 : o.y);
    const float rvl0 = c4 ? upd2 : (c3a ? p2 : 0.0f);
    const float rvl1 = c4 ? upd3 : (c3a ? p3 : 0.0f);
    const float rmv  = (c2 || c4) ? 1.0f : (c3a ? (float)(l + 1) : 0.0f);

    // ---- outputs, concatenated flat in return order ----
    float* rv_out   = out;
    float* rm_out   = out + (size_t)Bn * 32;
    float* rvel_out = out + (size_t)Bn * 48;
    float* rP_out   = out + (size_t)Bn * 80;

    reinterpret_cast<float2*>(rv_out)[tid]   = make_float2(rv0, rv1);
    rm_out[tid] = rmv;
    reinterpret_cast<float2*>(rvel_out)[tid] = make_float2(rvl0, rvl1);

    float4 w[4];
    #pragma unroll
    for (int i = 0; i < 4; ++i) {
        float e[4];
        #pragma unroll
        for (int j = 0; j < 4; ++j) {
            const float diag = (i == j) ? ((i < 2) ? 1.0f : 10.0f) : 0.0f;
            e[j] = c1 ? diag : (c3a ? pP[i][j] : (c4 ? Pn[i][j] : 0.0f));
        }
        w[i] = make_float4(e[0], e[1], e[2], e[3]);
    }
    float4* rPp = reinterpret_cast<float4*>(rP_out) + (size_t)tid * 4;
    rPp[0] = w[0]; rPp[1] = w[1]; rPp[2] = w[2]; rPp[3] = w[3];
}

extern "C" void kernel_launch(void* const* d_in, const int* in_sizes, int n_in,
                              void* d_out, int out_size, void* d_ws, size_t ws_size,
                              hipStream_t stream) {
    const float* value = (const float*)d_in[0];
    const float* vel   = (const float*)d_in[1];
    const float* P     = (const float*)d_in[2];
    const float* obs   = (const float*)d_in[3];
    const int*   lm    = (const int*)d_in[4];
    const int*   mask  = (const int*)d_in[5];

    const int Bn    = in_sizes[0] / (2 * NUM);   // value is (B, 2*NUM)
    const int total = Bn * NUM;

    kf_update_kernel<<<(total + 255) / 256, 256, 0, stream>>>(
        value, vel, P, obs, lm, mask, (float*)d_out, Bn);
}

// Round 2
// 177.792 us; speedup vs baseline: 1.0187x; 1.0187x over previous
//
#include <hip/hip_runtime.h>

#define NUM 16
#define TPB 256
// LDS floats per track: 16 data + 4 pad. Keeps every float4 chunk 16B-aligned
// (80 B stride) and breaks the 64-B bank aliasing (stride 20 mod 32 cycles
// through banks with <=2-way conflict, which is free on gfx950).
#define PSTRIDE 20

// One thread per (batch, track). P / rP go through LDS so every global
// memory instruction is lane-contiguous (1 KB per wave per instruction),
// fixing the 4x line-request amplification of the 64B-strided float4 pattern.
__global__ __launch_bounds__(TPB) void kf_update_kernel(
    const float* __restrict__ value,   // (B, 32)
    const float* __restrict__ vel,     // (B, 32)
    const float* __restrict__ Pin,     // (B, 16, 4, 4)
    const float* __restrict__ obs,     // (B, 32)
    const int*   __restrict__ lm,      // (B, 16)
    const int*   __restrict__ mask,    // (B, 16)
    float* __restrict__ out,           // rv(B*32) | rm(B*16) | rvel(B*32) | rP(B*256)
    int Bn)
{
    __shared__ float sm[TPB * PSTRIDE];   // 20 KB -> 8 blocks/CU

    const int tid   = threadIdx.x;
    const int gtid  = blockIdx.x * TPB + tid;
    const int total = Bn * NUM;
    const long long blockBase = (long long)blockIdx.x * TPB;  // first track of block
    const bool active = gtid < total;

    // ---- stage P: contiguous global float4 loads -> padded LDS ----
    {
        const float4* Pg = reinterpret_cast<const float4*>(Pin) + blockBase * 4;
        const long long limit = (long long)total * 4 - blockBase * 4;
        #pragma unroll
        for (int k = 0; k < 4; ++k) {
            const int g = tid + TPB * k;          // float4 index within block tile
            if (g < limit) {
                const float4 x = Pg[g];
                const int tr = g >> 2, part = g & 3;
                *reinterpret_cast<float4*>(&sm[tr * PSTRIDE + part * 4]) = x;
            }
        }
    }

    // ---- scalar per-track loads (coalesced already) ----
    float2 v = make_float2(0.f, 0.f), u = v, o = v;
    int l = 0, m = 0;
    if (active) {
        v = reinterpret_cast<const float2*>(value)[gtid];
        u = reinterpret_cast<const float2*>(vel)[gtid];
        o = reinterpret_cast<const float2*>(obs)[gtid];
        l = lm[gtid];
        m = mask[gtid];
    }

    __syncthreads();

    // ---- read own track's P from LDS (ds_read_b128, <=2-way banks) ----
    float Pm[16];
    #pragma unroll
    for (int c = 0; c < 4; ++c) {
        const float4 x = *reinterpret_cast<const float4*>(&sm[tid * PSTRIDE + c * 4]);
        Pm[c * 4 + 0] = x.x; Pm[c * 4 + 1] = x.y;
        Pm[c * 4 + 2] = x.z; Pm[c * 4 + 3] = x.w;
    }

    // ---- predict: pred = F @ [vx,vy,ux,uy] ----
    const float p0 = v.x + u.x;
    const float p1 = v.y + u.y;
    const float p2 = u.x;
    const float p3 = u.y;

    // ---- pP = F P F^T: row adds then col adds ----
    float Q[4][4];
    #pragma unroll
    for (int j = 0; j < 4; ++j) {
        Q[0][j] = Pm[0 * 4 + j] + Pm[2 * 4 + j];
        Q[1][j] = Pm[1 * 4 + j] + Pm[3 * 4 + j];
        Q[2][j] = Pm[2 * 4 + j];
        Q[3][j] = Pm[3 * 4 + j];
    }
    float pP[4][4];
    #pragma unroll
    for (int i = 0; i < 4; ++i) {
        pP[i][0] = Q[i][0] + Q[i][2];
        pP[i][1] = Q[i][1] + Q[i][3];
        pP[i][2] = Q[i][2];
        pP[i][3] = Q[i][3];
    }

    // ---- S = pP[:2,:2] + 1e-5 I, closed-form 2x2 inverse ----
    const float S00 = pP[0][0] + 1e-5f;
    const float S01 = pP[0][1];
    const float S10 = pP[1][0];
    const float S11 = pP[1][1] + 1e-5f;
    const float det  = S00 * S11 - S01 * S10;
    const float rdet = 1.0f / det;

    // ---- K = pP[:, :2] @ Sinv ----
    float K0[4], K1[4];
    #pragma unroll
    for (int i = 0; i < 4; ++i) {
        K0[i] = (pP[i][0] * S11 - pP[i][1] * S10) * rdet;
        K1[i] = (pP[i][1] * S00 - pP[i][0] * S01) * rdet;
    }

    // ---- state update ----
    const float y0 = o.x - p0;
    const float y1 = o.y - p1;
    const float upd0 = p0 + K0[0] * y0 + K1[0] * y1;
    const float upd1 = p1 + K0[1] * y0 + K1[1] * y1;
    const float upd2 = p2 + K0[2] * y0 + K1[2] * y1;
    const float upd3 = p3 + K0[3] * y0 + K1[3] * y1;

    // ---- Pn = pP - K @ pP[:2, :] ----
    float Pn[4][4];
    #pragma unroll
    for (int i = 0; i < 4; ++i) {
        #pragma unroll
        for (int j = 0; j < 4; ++j) {
            Pn[i][j] = pP[i][j] - (K0[i] * pP[0][j] + K1[i] * pP[1][j]);
        }
    }

    // ---- condition table ----
    const bool c1  = (l == 0) && (m == 0);
    const bool c2  = (l == 0) && (m != 0);
    const bool c3  = (l != 0) && (m == 0);
    const bool c4  = (l != 0) && (m != 0);
    const bool c3a = c3 && (l <= 5);

    const float rv0  = c4 ? upd0 : (c3 ? p0 : o.x);
    const float rv1  = c4 ? upd1 : (c3 ? p1 : o.y);
    const float rvl0 = c4 ? upd2 : (c3a ? p2 : 0.0f);
    const float rvl1 = c4 ? upd3 : (c3a ? p3 : 0.0f);
    const float rmv  = (c2 || c4) ? 1.0f : (c3a ? (float)(l + 1) : 0.0f);

    // ---- small outputs (already coalesced) ----
    float* rv_out   = out;
    float* rm_out   = out + (size_t)Bn * 32;
    float* rvel_out = out + (size_t)Bn * 48;
    float* rP_out   = out + (size_t)Bn * 80;

    if (active) {
        reinterpret_cast<float2*>(rv_out)[gtid]   = make_float2(rv0, rv1);
        rm_out[gtid] = rmv;
        reinterpret_cast<float2*>(rvel_out)[gtid] = make_float2(rvl0, rvl1);
    }

    __syncthreads();   // everyone done reading P tile; reuse sm for rP

    // ---- write own rP rows into LDS ----
    #pragma unroll
    for (int i = 0; i < 4; ++i) {
        float e[4];
        #pragma unroll
        for (int j = 0; j < 4; ++j) {
            const float diag = (i == j) ? ((i < 2) ? 1.0f : 10.0f) : 0.0f;
            e[j] = c1 ? diag : (c3a ? pP[i][j] : (c4 ? Pn[i][j] : 0.0f));
        }
        *reinterpret_cast<float4*>(&sm[tid * PSTRIDE + i * 4]) =
            make_float4(e[0], e[1], e[2], e[3]);
    }

    __syncthreads();

    // ---- drain rP tile: padded LDS -> contiguous global float4 stores ----
    {
        float4* rPg = reinterpret_cast<float4*>(rP_out) + blockBase * 4;
        const long long limit = (long long)total * 4 - blockBase * 4;
        #pragma unroll
        for (int k = 0; k < 4; ++k) {
            const int g = tid + TPB * k;
            if (g < limit) {
                const int tr = g >> 2, part = g & 3;
                rPg[g] = *reinterpret_cast<const float4*>(&sm[tr * PSTRIDE + part * 4]);
            }
        }
    }
}

extern "C" void kernel_launch(void* const* d_in, const int* in_sizes, int n_in,
                              void* d_out, int out_size, void* d_ws, size_t ws_size,
                              hipStream_t stream) {
    const float* value = (const float*)d_in[0];
    const float* vel   = (const float*)d_in[1];
    const float* P     = (const float*)d_in[2];
    const float* obs   = (const float*)d_in[3];
    const int*   lm    = (const int*)d_in[4];
    const int*   mask  = (const int*)d_in[5];

    const int Bn    = in_sizes[0] / (2 * NUM);   // value is (B, 2*NUM)
    const int total = Bn * NUM;
    const int blocks = (total + TPB - 1) / TPB;

    kf_update_kernel<<<blocks, TPB, 0, stream>>>(
        value, vel, P, obs, lm, mask, (float*)d_out, Bn);
}